// Round 2
// baseline (174.402 us; speedup 1.0000x reference)
//
#include <hip/hip_runtime.h>

#define IMG_W 1024
#define IMG_H 1024
#define ROWS  8          // output rows per block

typedef float v4f __attribute__((ext_vector_type(4)));   // native vector for nontemporal store

__global__ __launch_bounds__(256) void dir_rhs_kernel(
    const float* __restrict__ u,
    const float* __restrict__ f,
    const float* __restrict__ wt,
    float* __restrict__ out)
{
    // grid: 16 images * (1024/ROWS) row-tiles
    const int tile = blockIdx.x;
    const int b    = tile >> 7;              // 128 tiles per image
    const int r0   = (tile & 127) << 3;      // first output row of tile
    const int tid  = threadIdx.x;            // 0..255
    const int j0   = tid << 2;               // 4 columns per thread
    const size_t img = (size_t)b << 20;

    const float* ub = u   + img;
    const float* fb = f   + img;
    float*       ob = out + img;

    const bool le = (j0 == 0);               // covers col 0  (boundary in v)
    const bool re = (j0 + 4 >= IMG_W);       // covers col 1023

    // Broadcast weight loads (L1-cached)
    const float w00 = wt[0], w01 = wt[1], w02 = wt[2];
    const float w10 = wt[3], w11 = wt[4], w12 = wt[5];
    const float w20 = wt[6], w21 = wt[7], w22 = wt[8];
    const float cof = (float)(-(1.0 / 1023.0) * (1.0 / 1023.0) / 4.0);

    // Rolling 3-row register window (+1 prefetch row), 6 cols per thread
    float vm[6], vc[6], vp[6], nx[6];

    // Load v(r) = (r in [1,1022]) ? u row r with boundary cols zeroed : all zeros
    auto loadv = [&](float* a, int r) {
        if (r < 1 || r > IMG_H - 2) {        // wave-uniform branch
            #pragma unroll
            for (int q = 0; q < 6; q++) a[q] = 0.f;
            return;
        }
        const float* p = ub + (size_t)r * IMG_W;
        v4f c = *(const v4f*)(p + j0);
        a[1] = c.x; a[2] = c.y; a[3] = c.z; a[4] = c.w;
        a[0] = le ? 0.f : p[j0 - 1];
        a[5] = re ? 0.f : p[j0 + 4];
        if (le) a[1] = 0.f;                  // col 0 is boundary in v
        if (re) a[4] = 0.f;                  // col 1023 is boundary in v
    };

    loadv(vm, r0 - 1);
    loadv(vc, r0);
    loadv(vp, r0 + 1);

    #pragma unroll
    for (int k = 0; k < ROWS; k++) {
        const int r = r0 + k;

        // Prefetch the row needed NEXT iteration while we compute this one.
        loadv(nx, r + 2);

        v4f* o4 = (v4f*)(ob + (size_t)r * IMG_W + j0);

        if (r == 0 || r == IMG_H - 1) {
            // Dirichlet boundary rows
            v4f z = {0.f, 0.f, 0.f, 0.f};
            __builtin_nontemporal_store(z, o4);
        } else {
            v4f f4 = *(const v4f*)(fb + (size_t)r * IMG_W + j0);
            float ff[4] = {f4.x, f4.y, f4.z, f4.w};

            float res[4];
            #pragma unroll
            for (int e = 0; e < 4; e++) {
                float acc = cof * ff[e];
                acc += w00 * vm[e] + w01 * vm[e + 1] + w02 * vm[e + 2];
                acc += w10 * vc[e] + w11 * vc[e + 1] + w12 * vc[e + 2];
                acc += w20 * vp[e] + w21 * vp[e + 1] + w22 * vp[e + 2];
                res[e] = acc;
            }
            if (le) res[0] = 0.f;            // col 0 stays Dirichlet
            if (re) res[3] = 0.f;            // col 1023 stays Dirichlet

            v4f rv = {res[0], res[1], res[2], res[3]};
            __builtin_nontemporal_store(rv, o4);
        }

        // Shift the rolling window
        #pragma unroll
        for (int q = 0; q < 6; q++) { vm[q] = vc[q]; vc[q] = vp[q]; vp[q] = nx[q]; }
    }
}

extern "C" void kernel_launch(void* const* d_in, const int* in_sizes, int n_in,
                              void* d_out, int out_size, void* d_ws, size_t ws_size,
                              hipStream_t stream) {
    const float* u  = (const float*)d_in[0];
    const float* f  = (const float*)d_in[1];
    const float* wt = (const float*)d_in[2];
    float* out = (float*)d_out;

    const int B = 16;
    dim3 grid(B * (IMG_H / ROWS));   // 2048 blocks = 8 per CU, fully resident
    dim3 block(256);                 // 256 threads * 4 cols = 1024-wide tile
    dir_rhs_kernel<<<grid, block, 0, stream>>>(u, f, wt, out);
}